// Round 1
// baseline (463.889 us; speedup 1.0000x reference)
//
#include <hip/hip_runtime.h>
#include <hip/hip_bf16.h>
#include <cstdint>
#include <cstddef>

typedef __bf16 bf16;
typedef __bf16 bf16x8 __attribute__((ext_vector_type(8)));
typedef float f32x4 __attribute__((ext_vector_type(4)));
typedef unsigned int u32x4 __attribute__((ext_vector_type(4)));

#define DEVINL __device__ __forceinline__

namespace {
constexpr int Bb = 4, Ss = 2048, Ee = 1024, Hh = 16;
constexpr int Mm = Bb * Ss;      // 8192 rows
constexpr int N_QKV = 3 * Ee;    // 3072
}

DEVINL void gl_lds16(const bf16* g, bf16* l) {
  __builtin_amdgcn_global_load_lds((const __attribute__((address_space(1))) void*)g,
                                   (__attribute__((address_space(3))) void*)l, 16, 0, 0);
}

// ---------------- converters ----------------

__global__ void k_cvt_bf16(const float* __restrict__ in, bf16* __restrict__ out, int n) {
  int i = (blockIdx.x * 256 + threadIdx.x) * 8;
  if (i >= n) return;
  float4 a = *(const float4*)(in + i);
  float4 c = *(const float4*)(in + i + 4);
  bf16x8 v = {(bf16)a.x, (bf16)a.y, (bf16)a.z, (bf16)a.w,
              (bf16)c.x, (bf16)c.y, (bf16)c.z, (bf16)c.w};
  *(bf16x8*)(out + i) = v;
}

// out[c][r] = (bf16) in[r][c];  in: R x C f32 row-major. block (32,8), grid (C/32, R/32)
__global__ void k_transpose_cvt(const float* __restrict__ in, bf16* __restrict__ out, int R, int C) {
  __shared__ float tile[32][33];
  const int c0 = blockIdx.x * 32, r0 = blockIdx.y * 32;
  const int tx = threadIdx.x, ty = threadIdx.y;
  for (int i = 0; i < 32; i += 8)
    tile[ty + i][tx] = in[(size_t)(r0 + ty + i) * C + (c0 + tx)];
  __syncthreads();
  for (int i = 0; i < 32; i += 8)
    out[(size_t)(c0 + ty + i) * R + (r0 + tx)] = (bf16)tile[tx][ty + i];
}

// ---------------- GEMM (A row-major MxK, Bt row-major NxK, bf16, f32 accum) ----------------
// 128x128 tile, BK=64, 256 threads / 4 waves (2x2 wave grid, 64x64 per wave, 4x4 frags 16x16x32)

__global__ __launch_bounds__(256) void k_qkv_gemm(const bf16* __restrict__ A,
                                                  const bf16* __restrict__ Bt,
                                                  const float* __restrict__ bias,
                                                  bf16* __restrict__ out) {
  __shared__ bf16 sm[2 * 128 * 64];
  bf16* As = sm;
  bf16* Bs = sm + 128 * 64;
  const int tid = threadIdx.x, wid = tid >> 6, lane = tid & 63;
  const int wm = wid >> 1, wn = wid & 1;
  const int fr = lane & 15, kg = lane >> 4;
  const int m0 = blockIdx.y * 128, n0 = blockIdx.x * 128;
  const int K = Ee;

  f32x4 acc[4][4] = {};

  const int ar = wid * 32 + (lane >> 3);  // staging row base
  const int ac = (lane & 7) * 8;          // staging col (elems)
  const bf16* Ag = A + (size_t)(m0 + ar) * K + ac;
  const bf16* Bg = Bt + (size_t)(n0 + ar) * K + ac;
  bf16* AsW = As + wid * 32 * 64;
  bf16* BsW = Bs + wid * 32 * 64;

  for (int kt = 0; kt < K; kt += 64) {
    __syncthreads();
    for (int i = 0; i < 4; ++i) {
      gl_lds16(Ag + (size_t)(i * 8) * K + kt, AsW + i * 8 * 64);
      gl_lds16(Bg + (size_t)(i * 8) * K + kt, BsW + i * 8 * 64);
    }
    __syncthreads();
    for (int kk = 0; kk < 2; ++kk) {
      bf16x8 af[4], bfr[4];
      for (int mi = 0; mi < 4; ++mi)
        af[mi] = *(const bf16x8*)(As + (wm * 64 + mi * 16 + fr) * 64 + kk * 32 + kg * 8);
      for (int ni = 0; ni < 4; ++ni)
        bfr[ni] = *(const bf16x8*)(Bs + (wn * 64 + ni * 16 + fr) * 64 + kk * 32 + kg * 8);
      for (int mi = 0; mi < 4; ++mi)
        for (int ni = 0; ni < 4; ++ni)
          acc[mi][ni] = __builtin_amdgcn_mfma_f32_16x16x32_bf16(af[mi], bfr[ni], acc[mi][ni], 0, 0, 0);
    }
  }
  for (int ni = 0; ni < 4; ++ni) {
    const int col = n0 + wn * 64 + ni * 16 + fr;
    const float bv = bias[col];
    for (int mi = 0; mi < 4; ++mi) {
      const int mbase = m0 + wm * 64 + mi * 16 + kg * 4;
      for (int r = 0; r < 4; ++r)
        out[(size_t)(mbase + r) * N_QKV + col] = (bf16)(acc[mi][ni][r] + bv);
    }
  }
}

__global__ __launch_bounds__(256) void k_out_gemm(const bf16* __restrict__ A,
                                                  const bf16* __restrict__ Bt,
                                                  const float* __restrict__ bias,
                                                  float* __restrict__ out) {
  __shared__ bf16 sm[2 * 128 * 64];
  bf16* As = sm;
  bf16* Bs = sm + 128 * 64;
  const int tid = threadIdx.x, wid = tid >> 6, lane = tid & 63;
  const int wm = wid >> 1, wn = wid & 1;
  const int fr = lane & 15, kg = lane >> 4;
  const int m0 = blockIdx.y * 128, n0 = blockIdx.x * 128;
  const int K = Ee;

  f32x4 acc[4][4] = {};

  const int ar = wid * 32 + (lane >> 3);
  const int ac = (lane & 7) * 8;
  const bf16* Ag = A + (size_t)(m0 + ar) * K + ac;
  const bf16* Bg = Bt + (size_t)(n0 + ar) * K + ac;
  bf16* AsW = As + wid * 32 * 64;
  bf16* BsW = Bs + wid * 32 * 64;

  for (int kt = 0; kt < K; kt += 64) {
    __syncthreads();
    for (int i = 0; i < 4; ++i) {
      gl_lds16(Ag + (size_t)(i * 8) * K + kt, AsW + i * 8 * 64);
      gl_lds16(Bg + (size_t)(i * 8) * K + kt, BsW + i * 8 * 64);
    }
    __syncthreads();
    for (int kk = 0; kk < 2; ++kk) {
      bf16x8 af[4], bfr[4];
      for (int mi = 0; mi < 4; ++mi)
        af[mi] = *(const bf16x8*)(As + (wm * 64 + mi * 16 + fr) * 64 + kk * 32 + kg * 8);
      for (int ni = 0; ni < 4; ++ni)
        bfr[ni] = *(const bf16x8*)(Bs + (wn * 64 + ni * 16 + fr) * 64 + kk * 32 + kg * 8);
      for (int mi = 0; mi < 4; ++mi)
        for (int ni = 0; ni < 4; ++ni)
          acc[mi][ni] = __builtin_amdgcn_mfma_f32_16x16x32_bf16(af[mi], bfr[ni], acc[mi][ni], 0, 0, 0);
    }
  }
  for (int ni = 0; ni < 4; ++ni) {
    const int col = n0 + wn * 64 + ni * 16 + fr;
    const float bv = bias[col];
    for (int mi = 0; mi < 4; ++mi) {
      const int mbase = m0 + wm * 64 + mi * 16 + kg * 4;
      for (int r = 0; r < 4; ++r)
        out[(size_t)(mbase + r) * Ee + col] = acc[mi][ni][r] + bv;
    }
  }
}

// ---------------- flash attention (causal, scale=1/32) ----------------
// qkv: [B,S,H,3D] bf16 (row = 3072). grid (S/64, H, B), 256 threads / 4 waves.
// Each wave owns 16 q-rows; KV tile = 64. K/V staged to LDS with XOR chunk swizzle.

__global__ __launch_bounds__(256) void k_attn(const bf16* __restrict__ qkv, bf16* __restrict__ vals) {
  constexpr float SCALE = 0.03125f;  // 1/sqrt(E) = 1/32
  const int qt = blockIdx.x, h = blockIdx.y, b = blockIdx.z;
  const int q0 = qt * 64;
  const int tid = threadIdx.x;
  const int wid = tid >> 6, lane = tid & 63;
  const int fr = lane & 15, kg = lane >> 4;

  __shared__ bf16 Ks[64 * 64];      // [key][d], chunk-swizzled
  __shared__ bf16 Vt[64 * 64];      // [d][key], chunk-swizzled
  __shared__ bf16 Ps[4][16 * 64];   // per-wave P strip [qrow][key], chunk-swizzled

  const size_t rstr = (size_t)N_QKV;  // 3072
  const bf16* base = qkv + (size_t)b * Ss * rstr + h * 192;

  // Q fragments held in registers for the whole kernel
  bf16x8 aq[2];
  {
    const bf16* qrow = base + (size_t)(q0 + wid * 16 + fr) * rstr;
    aq[0] = *(const bf16x8*)(qrow + kg * 8);
    aq[1] = *(const bf16x8*)(qrow + 32 + kg * 8);
  }

  float m_run[4], l_run[4];
  f32x4 o_acc[4] = {};
  for (int r = 0; r < 4; ++r) { m_run[r] = -1e30f; l_run[r] = 0.f; }

  const int kv_tiles = qt + 1;
  for (int it = 0; it < kv_tiles; ++it) {
    const int kv0 = it * 64;
    __syncthreads();  // protect Ks/Vt (prev tile's reads done)
    // stage K (swizzled) and V (transposed + swizzled)
    for (int t = 0; t < 2; ++t) {
      const int tau = tid + t * 256;
      const int row = tau >> 3, c = tau & 7;  // row = key, c = 16B chunk
      const bf16* src = base + (size_t)(kv0 + row) * rstr;
      u32x4 kv16 = *(const u32x4*)(src + 64 + c * 8);
      *(u32x4*)((char*)Ks + row * 128 + ((c ^ (row & 7)) * 16)) = kv16;
      u32x4 vv16 = *(const u32x4*)(src + 128 + c * 8);
      const unsigned short* vsv = (const unsigned short*)&vv16;
      for (int j = 0; j < 8; ++j) {
        const int d = c * 8 + j;
        *(unsigned short*)((char*)Vt + d * 128 + (((row >> 3) ^ (d & 7)) * 16) + (row & 7) * 2) = vsv[j];
      }
    }
    __syncthreads();

    // S = Q K^T  (16 q-rows x 64 keys per wave)
    f32x4 sacc[4] = {};
    for (int kk = 0; kk < 2; ++kk)
      for (int ni = 0; ni < 4; ++ni) {
        const int rowb = ni * 16 + fr;
        bf16x8 bk = *(const bf16x8*)((const char*)Ks + rowb * 128 + (((kk * 4 + kg) ^ (rowb & 7)) * 16));
        sacc[ni] = __builtin_amdgcn_mfma_f32_16x16x32_bf16(aq[kk], bk, sacc[ni], 0, 0, 0);
      }

    // online softmax on the strip
    float p[4][4], pm[4];
    const int q_glob = q0 + wid * 16 + kg * 4;  // + r
    for (int r = 0; r < 4; ++r) pm[r] = -1e30f;
    const bool diag = (kv0 == q0);
    for (int ni = 0; ni < 4; ++ni) {
      const int kcol = kv0 + ni * 16 + fr;
      for (int r = 0; r < 4; ++r) {
        float s = sacc[ni][r] * SCALE;
        if (diag && kcol > q_glob + r) s = -1e30f;
        p[ni][r] = s;
        pm[r] = fmaxf(pm[r], s);
      }
    }
    for (int mask = 1; mask < 16; mask <<= 1)
      for (int r = 0; r < 4; ++r)
        pm[r] = fmaxf(pm[r], __shfl_xor(pm[r], mask, 64));
    float f[4], rs[4];
    for (int r = 0; r < 4; ++r) {
      const float mn = fmaxf(m_run[r], pm[r]);
      f[r] = __expf(m_run[r] - mn);
      m_run[r] = mn;
      rs[r] = 0.f;
    }
    for (int ni = 0; ni < 4; ++ni)
      for (int r = 0; r < 4; ++r) {
        const float e = __expf(p[ni][r] - m_run[r]);
        p[ni][r] = e;
        rs[r] += e;
      }
    for (int mask = 1; mask < 16; mask <<= 1)
      for (int r = 0; r < 4; ++r)
        rs[r] += __shfl_xor(rs[r], mask, 64);
    for (int r = 0; r < 4; ++r) l_run[r] = l_run[r] * f[r] + rs[r];
    for (int ni = 0; ni < 4; ++ni)
      for (int r = 0; r < 4; ++r)
        o_acc[ni][r] *= f[r];

    // P -> LDS (bf16, swizzled for A-layout reads)
    bf16* Pw = Ps[wid];
    for (int ni = 0; ni < 4; ++ni)
      for (int r = 0; r < 4; ++r) {
        const int prow = kg * 4 + r;
        const int pcol = ni * 16 + fr;
        *(bf16*)((char*)Pw + prow * 128 + (((pcol >> 3) ^ (prow & 7)) * 16) + (pcol & 7) * 2) =
            (bf16)p[ni][r];
      }
    __syncthreads();

    // O += P V
    for (int kk = 0; kk < 2; ++kk) {
      bf16x8 ap = *(const bf16x8*)((const char*)Pw + fr * 128 + (((kk * 4 + kg) ^ (fr & 7)) * 16));
      for (int ni = 0; ni < 4; ++ni) {
        const int rowb = ni * 16 + fr;
        bf16x8 bv = *(const bf16x8*)((const char*)Vt + rowb * 128 + (((kk * 4 + kg) ^ (rowb & 7)) * 16));
        o_acc[ni] = __builtin_amdgcn_mfma_f32_16x16x32_bf16(ap, bv, o_acc[ni], 0, 0, 0);
      }
    }
  }

  // epilogue: vals[B,S,H,D]
  for (int ni = 0; ni < 4; ++ni)
    for (int r = 0; r < 4; ++r) {
      const int s = q0 + wid * 16 + kg * 4 + r;
      const int e = h * 64 + ni * 16 + fr;
      const float v = o_acc[ni][r] / l_run[r];
      vals[((size_t)b * Ss + s) * Ee + e] = (bf16)v;
    }
}

// ---------------- launch ----------------

extern "C" void kernel_launch(void* const* d_in, const int* in_sizes, int n_in,
                              void* d_out, int out_size, void* d_ws, size_t ws_size,
                              hipStream_t stream) {
  const float* x    = (const float*)d_in[0];
  const float* Wqkv = (const float*)d_in[1];
  const float* bqkv = (const float*)d_in[2];
  const float* Wout = (const float*)d_in[3];
  const float* bout = (const float*)d_in[4];
  float* out = (float*)d_out;

  // workspace layout (total 92,274,688 B)
  char* ws = (char*)d_ws;
  bf16* x_bf  = (bf16*)(ws);                               // 16 MiB  [8192,1024]
  bf16* WqkvT = (bf16*)(ws + (size_t)16777216);            //  6 MiB  [3072,1024]
  bf16* WoutT = (bf16*)(ws + (size_t)16777216 + 6291456);  //  2 MiB  [1024,1024]
  bf16* qkvb  = (bf16*)(ws + (size_t)25165824);            // 48 MiB  [8192,3072]
  bf16* valsb = (bf16*)(ws + (size_t)75497472);            // 16 MiB  [8192,1024]

  k_cvt_bf16<<<dim3(Mm * Ee / 2048), dim3(256), 0, stream>>>(x, x_bf, Mm * Ee);
  k_transpose_cvt<<<dim3(N_QKV / 32, Ee / 32), dim3(32, 8), 0, stream>>>(Wqkv, WqkvT, Ee, N_QKV);
  k_transpose_cvt<<<dim3(Ee / 32, Ee / 32), dim3(32, 8), 0, stream>>>(Wout, WoutT, Ee, Ee);
  k_qkv_gemm<<<dim3(N_QKV / 128, Mm / 128), dim3(256), 0, stream>>>(x_bf, WqkvT, bqkv, qkvb);
  k_attn<<<dim3(Ss / 64, Hh, Bb), dim3(256), 0, stream>>>(qkvb, valsb);
  k_out_gemm<<<dim3(Ee / 128, Mm / 128), dim3(256), 0, stream>>>(valsb, WoutT, bout, out);
}

// Round 2
// 366.385 us; speedup vs baseline: 1.2661x; 1.2661x over previous
//
#include <hip/hip_runtime.h>
#include <hip/hip_bf16.h>
#include <cstdint>
#include <cstddef>

typedef __bf16 bf16;
typedef __bf16 bf16x8 __attribute__((ext_vector_type(8)));
typedef float f32x4 __attribute__((ext_vector_type(4)));
typedef unsigned int u32x4 __attribute__((ext_vector_type(4)));

#define DEVINL __device__ __forceinline__

namespace {
constexpr int Bb = 4, Ss = 2048, Ee = 1024, Hh = 16;
constexpr int Mm = Bb * Ss;      // 8192 rows
constexpr int N_QKV = 3 * Ee;    // 3072
}

DEVINL void gl_lds16(const bf16* g, bf16* l) {
  __builtin_amdgcn_global_load_lds((const __attribute__((address_space(1))) void*)g,
                                   (__attribute__((address_space(3))) void*)l, 16, 0, 0);
}

// ---------------- converters ----------------

__global__ void k_cvt_bf16(const float* __restrict__ in, bf16* __restrict__ out, int n) {
  int i = (blockIdx.x * 256 + threadIdx.x) * 8;
  if (i >= n) return;
  float4 a = *(const float4*)(in + i);
  float4 c = *(const float4*)(in + i + 4);
  bf16x8 v = {(bf16)a.x, (bf16)a.y, (bf16)a.z, (bf16)a.w,
              (bf16)c.x, (bf16)c.y, (bf16)c.z, (bf16)c.w};
  *(bf16x8*)(out + i) = v;
}

// out[c][r] = (bf16) in[r][c];  in: R x C f32 row-major. block (32,8), grid (C/32, R/32)
__global__ void k_transpose_cvt(const float* __restrict__ in, bf16* __restrict__ out, int R, int C) {
  __shared__ float tile[32][33];
  const int c0 = blockIdx.x * 32, r0 = blockIdx.y * 32;
  const int tx = threadIdx.x, ty = threadIdx.y;
  for (int i = 0; i < 32; i += 8)
    tile[ty + i][tx] = in[(size_t)(r0 + ty + i) * C + (c0 + tx)];
  __syncthreads();
  for (int i = 0; i < 32; i += 8)
    out[(size_t)(c0 + ty + i) * R + (r0 + tx)] = (bf16)tile[tx][ty + i];
}

// V^T extract: vt[b,h,d,s] = qkv[b,s,h*192 + 128 + d].  block (32,8), grid (S/32, D/32=2, B*H)
__global__ void k_vt(const bf16* __restrict__ qkvb, bf16* __restrict__ vt) {
  __shared__ bf16 t[32][33];
  const int bh = blockIdx.z;
  const int b = bh >> 4, h = bh & 15;
  const int s0 = blockIdx.x * 32, d0 = blockIdx.y * 32;
  const int tx = threadIdx.x, ty = threadIdx.y;
  const bf16* src = qkvb + (size_t)b * Ss * N_QKV + h * 192 + 128;
  for (int i = 0; i < 32; i += 8)
    t[ty + i][tx] = src[(size_t)(s0 + ty + i) * N_QKV + d0 + tx];
  __syncthreads();
  bf16* dst = vt + ((size_t)bh * 64 + d0) * Ss + s0;
  for (int i = 0; i < 32; i += 8)
    dst[(size_t)(ty + i) * Ss + tx] = t[tx][ty + i];
}

// ---------------- GEMM (A row-major MxK, Bt row-major NxK, bf16, f32 accum) ----------------

__global__ __launch_bounds__(256) void k_qkv_gemm(const bf16* __restrict__ A,
                                                  const bf16* __restrict__ Bt,
                                                  const float* __restrict__ bias,
                                                  bf16* __restrict__ out) {
  __shared__ bf16 sm[2 * 128 * 64];
  bf16* As = sm;
  bf16* Bs = sm + 128 * 64;
  const int tid = threadIdx.x, wid = tid >> 6, lane = tid & 63;
  const int wm = wid >> 1, wn = wid & 1;
  const int fr = lane & 15, kg = lane >> 4;
  const int m0 = blockIdx.y * 128, n0 = blockIdx.x * 128;
  const int K = Ee;

  f32x4 acc[4][4] = {};

  const int ar = wid * 32 + (lane >> 3);
  const int ac = (lane & 7) * 8;
  const bf16* Ag = A + (size_t)(m0 + ar) * K + ac;
  const bf16* Bg = Bt + (size_t)(n0 + ar) * K + ac;
  bf16* AsW = As + wid * 32 * 64;
  bf16* BsW = Bs + wid * 32 * 64;

  for (int kt = 0; kt < K; kt += 64) {
    __syncthreads();
    for (int i = 0; i < 4; ++i) {
      gl_lds16(Ag + (size_t)(i * 8) * K + kt, AsW + i * 8 * 64);
      gl_lds16(Bg + (size_t)(i * 8) * K + kt, BsW + i * 8 * 64);
    }
    __syncthreads();
    for (int kk = 0; kk < 2; ++kk) {
      bf16x8 af[4], bfr[4];
      for (int mi = 0; mi < 4; ++mi)
        af[mi] = *(const bf16x8*)(As + (wm * 64 + mi * 16 + fr) * 64 + kk * 32 + kg * 8);
      for (int ni = 0; ni < 4; ++ni)
        bfr[ni] = *(const bf16x8*)(Bs + (wn * 64 + ni * 16 + fr) * 64 + kk * 32 + kg * 8);
      for (int mi = 0; mi < 4; ++mi)
        for (int ni = 0; ni < 4; ++ni)
          acc[mi][ni] = __builtin_amdgcn_mfma_f32_16x16x32_bf16(af[mi], bfr[ni], acc[mi][ni], 0, 0, 0);
    }
  }
  for (int ni = 0; ni < 4; ++ni) {
    const int col = n0 + wn * 64 + ni * 16 + fr;
    const float bv = bias[col];
    for (int mi = 0; mi < 4; ++mi) {
      const int mbase = m0 + wm * 64 + mi * 16 + kg * 4;
      for (int r = 0; r < 4; ++r)
        out[(size_t)(mbase + r) * N_QKV + col] = (bf16)(acc[mi][ni][r] + bv);
    }
  }
}

__global__ __launch_bounds__(256) void k_out_gemm(const bf16* __restrict__ A,
                                                  const bf16* __restrict__ Bt,
                                                  const float* __restrict__ bias,
                                                  float* __restrict__ out) {
  __shared__ bf16 sm[2 * 128 * 64];
  bf16* As = sm;
  bf16* Bs = sm + 128 * 64;
  const int tid = threadIdx.x, wid = tid >> 6, lane = tid & 63;
  const int wm = wid >> 1, wn = wid & 1;
  const int fr = lane & 15, kg = lane >> 4;
  const int m0 = blockIdx.y * 128, n0 = blockIdx.x * 128;
  const int K = Ee;

  f32x4 acc[4][4] = {};

  const int ar = wid * 32 + (lane >> 3);
  const int ac = (lane & 7) * 8;
  const bf16* Ag = A + (size_t)(m0 + ar) * K + ac;
  const bf16* Bg = Bt + (size_t)(n0 + ar) * K + ac;
  bf16* AsW = As + wid * 32 * 64;
  bf16* BsW = Bs + wid * 32 * 64;

  for (int kt = 0; kt < K; kt += 64) {
    __syncthreads();
    for (int i = 0; i < 4; ++i) {
      gl_lds16(Ag + (size_t)(i * 8) * K + kt, AsW + i * 8 * 64);
      gl_lds16(Bg + (size_t)(i * 8) * K + kt, BsW + i * 8 * 64);
    }
    __syncthreads();
    for (int kk = 0; kk < 2; ++kk) {
      bf16x8 af[4], bfr[4];
      for (int mi = 0; mi < 4; ++mi)
        af[mi] = *(const bf16x8*)(As + (wm * 64 + mi * 16 + fr) * 64 + kk * 32 + kg * 8);
      for (int ni = 0; ni < 4; ++ni)
        bfr[ni] = *(const bf16x8*)(Bs + (wn * 64 + ni * 16 + fr) * 64 + kk * 32 + kg * 8);
      for (int mi = 0; mi < 4; ++mi)
        for (int ni = 0; ni < 4; ++ni)
          acc[mi][ni] = __builtin_amdgcn_mfma_f32_16x16x32_bf16(af[mi], bfr[ni], acc[mi][ni], 0, 0, 0);
    }
  }
  for (int ni = 0; ni < 4; ++ni) {
    const int col = n0 + wn * 64 + ni * 16 + fr;
    const float bv = bias[col];
    for (int mi = 0; mi < 4; ++mi) {
      const int mbase = m0 + wm * 64 + mi * 16 + kg * 4;
      for (int r = 0; r < 4; ++r)
        out[(size_t)(mbase + r) * Ee + col] = acc[mi][ni][r] + bv;
    }
  }
}

// ---------------- flash attention (causal, scale=1/32) ----------------
// q-block 128 (4 waves x 32 q-rows), KV tile 64, double-buffered K/V^T staging via
// global_load_lds with pre-swizzled sources; ONE barrier per tile; P per-wave via LDS.

__global__ __launch_bounds__(256, 2) void k_attn(const bf16* __restrict__ qkv,
                                                 const bf16* __restrict__ vt,
                                                 bf16* __restrict__ vals) {
  constexpr float SC = 0.03125f * 1.44269504f;  // (1/sqrt(E)) * log2(e)
  const int qt = blockIdx.x, h = blockIdx.y, b = blockIdx.z;
  const int q0 = qt * 128;
  const int tid = threadIdx.x, w = tid >> 6, lane = tid & 63;
  const int fr = lane & 15, kg = lane >> 4;
  const int rl = lane >> 3, cl = (lane & 7) ^ (lane >> 3);

  __shared__ bf16 KsB[2][4096];   // [key 64][chunk-swizzled d 64]
  __shared__ bf16 VtB[2][4096];   // [d 64][chunk-swizzled s 64]
  __shared__ bf16 Ps[4][2048];    // per-wave [qrow 32][chunk-swizzled k 64]

  const bf16* base = qkv + (size_t)b * Ss * N_QKV + h * 192;
  const bf16* kb = base + 64 + (size_t)rl * N_QKV + cl * 8;                      // +(kv0+i*8)*3072
  const bf16* vb = vt + (size_t)(b * Hh + h) * 64 * Ss + (size_t)rl * Ss + cl * 8;  // +i*8*2048 + kv0

  // Q fragments in registers (32 rows/wave)
  bf16x8 aq[2][2];
  for (int sub = 0; sub < 2; ++sub) {
    const bf16* qr = base + (size_t)(q0 + w * 32 + sub * 16 + fr) * N_QKV + kg * 8;
    aq[sub][0] = *(const bf16x8*)(qr);
    aq[sub][1] = *(const bf16x8*)(qr + 32);
  }

  float m_run[2][4], l_run[2][4];
  f32x4 o_acc[2][4] = {};
  for (int s2 = 0; s2 < 2; ++s2)
    for (int r = 0; r < 4; ++r) { m_run[s2][r] = -1e30f; l_run[s2][r] = 0.f; }

  const int nt = 2 * qt + 2;

  // prologue: stage tile 0 into buf 0
  for (int t = 0; t < 2; ++t) {
    const int i = w * 2 + t;
    gl_lds16(kb + (size_t)(i * 8) * N_QKV, KsB[0] + i * 512);
    gl_lds16(vb + (size_t)(i * 8) * Ss, VtB[0] + i * 512);
  }

  int cur = 0;
  for (int it = 0; it < nt; ++it) {
    const int kv0 = it * 64;
    __syncthreads();  // drains vmcnt: stage(it) complete; prev-tile reads done
    if (it + 1 < nt) {
      const int kvn = kv0 + 64;
      for (int t = 0; t < 2; ++t) {
        const int i = w * 2 + t;
        gl_lds16(kb + (size_t)(kvn + i * 8) * N_QKV, KsB[cur ^ 1] + i * 512);
        gl_lds16(vb + (size_t)(i * 8) * Ss + kvn, VtB[cur ^ 1] + i * 512);
      }
    }
    const bool active = (kv0 <= q0 + w * 32 + 31);  // wave-uniform: any unmasked row?
    if (active) {
      // ---- QK^T ----
      f32x4 sacc[2][4] = {};
      for (int kk = 0; kk < 2; ++kk) {
        bf16x8 bk[4];
        for (int ni = 0; ni < 4; ++ni) {
          const int rb = ni * 16 + fr;
          bk[ni] = *(const bf16x8*)(KsB[cur] + rb * 64 + (((kk * 4 + kg) ^ (rb & 7)) * 8));
        }
        __builtin_amdgcn_s_setprio(1);
        for (int sub = 0; sub < 2; ++sub)
          for (int ni = 0; ni < 4; ++ni)
            sacc[sub][ni] =
                __builtin_amdgcn_mfma_f32_16x16x32_bf16(aq[sub][kk], bk[ni], sacc[sub][ni], 0, 0, 0);
        __builtin_amdgcn_s_setprio(0);
      }
      // ---- online softmax (exp2 domain) ----
      for (int sub = 0; sub < 2; ++sub) {
        const int qs = q0 + w * 32 + sub * 16;
        float pm[4] = {-1e30f, -1e30f, -1e30f, -1e30f};
        float p[4][4];
        if (kv0 + 63 > qs) {
          for (int ni = 0; ni < 4; ++ni) {
            const int kc = kv0 + ni * 16 + fr;
            for (int r = 0; r < 4; ++r) {
              float s = sacc[sub][ni][r] * SC;
              if (kc > qs + kg * 4 + r) s = -1e30f;
              p[ni][r] = s;
              pm[r] = fmaxf(pm[r], s);
            }
          }
        } else {
          for (int ni = 0; ni < 4; ++ni)
            for (int r = 0; r < 4; ++r) {
              float s = sacc[sub][ni][r] * SC;
              p[ni][r] = s;
              pm[r] = fmaxf(pm[r], s);
            }
        }
        for (int msk = 1; msk < 16; msk <<= 1)
          for (int r = 0; r < 4; ++r)
            pm[r] = fmaxf(pm[r], __shfl_xor(pm[r], msk, 64));
        float rs[4];
        for (int r = 0; r < 4; ++r) {
          const float mn = fmaxf(m_run[sub][r], pm[r]);
          const float f = exp2f(m_run[sub][r] - mn);
          m_run[sub][r] = mn;
          l_run[sub][r] *= f;
          for (int ni = 0; ni < 4; ++ni) o_acc[sub][ni][r] *= f;
          rs[r] = 0.f;
        }
        for (int ni = 0; ni < 4; ++ni)
          for (int r = 0; r < 4; ++r) {
            const float e = exp2f(p[ni][r] - m_run[sub][r]);
            p[ni][r] = e;
            rs[r] += e;
          }
        for (int msk = 1; msk < 16; msk <<= 1)
          for (int r = 0; r < 4; ++r)
            rs[r] += __shfl_xor(rs[r], msk, 64);
        for (int r = 0; r < 4; ++r) l_run[sub][r] += rs[r];
        // P -> per-wave LDS strip (swizzled); same-wave ordering, no barrier needed
        for (int ni = 0; ni < 4; ++ni) {
          const int kloc = ni * 16 + fr;
          const int ch = kloc >> 3, off = kloc & 7;
          for (int r = 0; r < 4; ++r) {
            const int qr = sub * 16 + kg * 4 + r;
            Ps[w][qr * 64 + ((ch ^ (qr & 7)) * 8) + off] = (bf16)p[ni][r];
          }
        }
      }
      // ---- O += P V ----
      for (int kk = 0; kk < 2; ++kk) {
        bf16x8 ap[2], bv[4];
        for (int sub = 0; sub < 2; ++sub) {
          const int pr = sub * 16 + fr;
          ap[sub] = *(const bf16x8*)(Ps[w] + pr * 64 + (((kk * 4 + kg) ^ (pr & 7)) * 8));
        }
        for (int ni = 0; ni < 4; ++ni) {
          const int rb = ni * 16 + fr;
          bv[ni] = *(const bf16x8*)(VtB[cur] + rb * 64 + (((kk * 4 + kg) ^ (rb & 7)) * 8));
        }
        __builtin_amdgcn_s_setprio(1);
        for (int sub = 0; sub < 2; ++sub)
          for (int ni = 0; ni < 4; ++ni)
            o_acc[sub][ni] =
                __builtin_amdgcn_mfma_f32_16x16x32_bf16(ap[sub], bv[ni], o_acc[sub][ni], 0, 0, 0);
        __builtin_amdgcn_s_setprio(0);
      }
    }
    cur ^= 1;
  }

  // epilogue: vals[b,s,h*64+d]
  for (int sub = 0; sub < 2; ++sub)
    for (int r = 0; r < 4; ++r) {
      const float inv = 1.f / l_run[sub][r];
      const int q = q0 + w * 32 + sub * 16 + kg * 4 + r;
      bf16* dst = vals + ((size_t)b * Ss + q) * Ee + h * 64;
      for (int ni = 0; ni < 4; ++ni)
        dst[ni * 16 + fr] = (bf16)(o_acc[sub][ni][r] * inv);
    }
}

// ---------------- launch ----------------

extern "C" void kernel_launch(void* const* d_in, const int* in_sizes, int n_in,
                              void* d_out, int out_size, void* d_ws, size_t ws_size,
                              hipStream_t stream) {
  const float* x    = (const float*)d_in[0];
  const float* Wqkv = (const float*)d_in[1];
  const float* bqkv = (const float*)d_in[2];
  const float* Wout = (const float*)d_in[3];
  const float* bout = (const float*)d_in[4];
  float* out = (float*)d_out;

  // workspace layout (92 MiB). vt reuses x_bf's region (x_bf dead after k_qkv_gemm).
  char* ws = (char*)d_ws;
  bf16* x_bf  = (bf16*)(ws);                               // 16 MiB  [8192,1024]
  bf16* vt    = (bf16*)(ws);                               // 16 MiB  [64,64,2048] (b*h, d, s)
  bf16* WqkvT = (bf16*)(ws + (size_t)16777216);            //  6 MiB  [3072,1024]
  bf16* WoutT = (bf16*)(ws + (size_t)16777216 + 6291456);  //  2 MiB  [1024,1024]
  bf16* qkvb  = (bf16*)(ws + (size_t)25165824);            // 48 MiB  [8192,3072]
  bf16* valsb = (bf16*)(ws + (size_t)75497472);            // 16 MiB  [8192,1024]

  k_cvt_bf16<<<dim3(Mm * Ee / 2048), dim3(256), 0, stream>>>(x, x_bf, Mm * Ee);
  k_transpose_cvt<<<dim3(N_QKV / 32, Ee / 32), dim3(32, 8), 0, stream>>>(Wqkv, WqkvT, Ee, N_QKV);
  k_transpose_cvt<<<dim3(Ee / 32, Ee / 32), dim3(32, 8), 0, stream>>>(Wout, WoutT, Ee, Ee);
  k_qkv_gemm<<<dim3(N_QKV / 128, Mm / 128), dim3(256), 0, stream>>>(x_bf, WqkvT, bqkv, qkvb);
  k_vt<<<dim3(Ss / 32, 2, Bb * Hh), dim3(32, 8), 0, stream>>>(qkvb, vt);
  k_attn<<<dim3(Ss / 128, Hh, Bb), dim3(256), 0, stream>>>(qkvb, vt, valsb);
  k_out_gemm<<<dim3(Ee / 128, Mm / 128), dim3(256), 0, stream>>>(valsb, WoutT, bout, out);
}

// Round 3
// 264.176 us; speedup vs baseline: 1.7560x; 1.3869x over previous
//
#include <hip/hip_runtime.h>
#include <hip/hip_bf16.h>
#include <cstdint>
#include <cstddef>

typedef __bf16 bf16;
typedef __bf16 bf16x8 __attribute__((ext_vector_type(8)));
typedef float f32x4 __attribute__((ext_vector_type(4)));
typedef unsigned int u32x4 __attribute__((ext_vector_type(4)));

#define DEVINL __device__ __forceinline__

namespace {
constexpr int Bb = 4, Ss = 2048, Ee = 1024, Hh = 16;
constexpr int Mm = Bb * Ss;      // 8192 rows
constexpr int N_QKV = 3 * Ee;    // 3072
}

DEVINL void gl_lds16(const bf16* g, bf16* l) {
  __builtin_amdgcn_global_load_lds((const __attribute__((address_space(1))) void*)g,
                                   (__attribute__((address_space(3))) void*)l, 16, 0, 0);
}

// ---------------- converters ----------------

__global__ void k_cvt_bf16(const float* __restrict__ in, bf16* __restrict__ out, int n) {
  int i = (blockIdx.x * 256 + threadIdx.x) * 8;
  if (i >= n) return;
  float4 a = *(const float4*)(in + i);
  float4 c = *(const float4*)(in + i + 4);
  bf16x8 v = {(bf16)a.x, (bf16)a.y, (bf16)a.z, (bf16)a.w,
              (bf16)c.x, (bf16)c.y, (bf16)c.z, (bf16)c.w};
  *(bf16x8*)(out + i) = v;
}

// out[c][r] = (bf16) in[r][c];  in: R x C f32 row-major. block (32,8), grid (C/32, R/32)
__global__ void k_transpose_cvt(const float* __restrict__ in, bf16* __restrict__ out, int R, int C) {
  __shared__ float tile[32][33];
  const int c0 = blockIdx.x * 32, r0 = blockIdx.y * 32;
  const int tx = threadIdx.x, ty = threadIdx.y;
  for (int i = 0; i < 32; i += 8)
    tile[ty + i][tx] = in[(size_t)(r0 + ty + i) * C + (c0 + tx)];
  __syncthreads();
  for (int i = 0; i < 32; i += 8)
    out[(size_t)(c0 + ty + i) * R + (r0 + tx)] = (bf16)tile[tx][ty + i];
}

// V^T extract: vt[b,h,d,s] = qkv[b,s,h*192 + 128 + d].  block (32,8), grid (S/32, D/32=2, B*H)
__global__ void k_vt(const bf16* __restrict__ qkvb, bf16* __restrict__ vt) {
  __shared__ bf16 t[32][33];
  const int bh = blockIdx.z;
  const int b = bh >> 4, h = bh & 15;
  const int s0 = blockIdx.x * 32, d0 = blockIdx.y * 32;
  const int tx = threadIdx.x, ty = threadIdx.y;
  const bf16* src = qkvb + (size_t)b * Ss * N_QKV + h * 192 + 128;
  for (int i = 0; i < 32; i += 8)
    t[ty + i][tx] = src[(size_t)(s0 + ty + i) * N_QKV + d0 + tx];
  __syncthreads();
  bf16* dst = vt + ((size_t)bh * 64 + d0) * Ss + s0;
  for (int i = 0; i < 32; i += 8)
    dst[(size_t)(ty + i) * Ss + tx] = t[tx][ty + i];
}

// ---------------- GEMM (A row-major MxK, Bt row-major NxK, bf16, f32 accum) ----------------

__global__ __launch_bounds__(256) void k_qkv_gemm(const bf16* __restrict__ A,
                                                  const bf16* __restrict__ Bt,
                                                  const float* __restrict__ bias,
                                                  bf16* __restrict__ out) {
  __shared__ bf16 sm[2 * 128 * 64];
  bf16* As = sm;
  bf16* Bs = sm + 128 * 64;
  const int tid = threadIdx.x, wid = tid >> 6, lane = tid & 63;
  const int wm = wid >> 1, wn = wid & 1;
  const int fr = lane & 15, kg = lane >> 4;
  const int m0 = blockIdx.y * 128, n0 = blockIdx.x * 128;
  const int K = Ee;

  f32x4 acc[4][4] = {};

  const int ar = wid * 32 + (lane >> 3);
  const int ac = (lane & 7) * 8;
  const bf16* Ag = A + (size_t)(m0 + ar) * K + ac;
  const bf16* Bg = Bt + (size_t)(n0 + ar) * K + ac;
  bf16* AsW = As + wid * 32 * 64;
  bf16* BsW = Bs + wid * 32 * 64;

  for (int kt = 0; kt < K; kt += 64) {
    __syncthreads();
    for (int i = 0; i < 4; ++i) {
      gl_lds16(Ag + (size_t)(i * 8) * K + kt, AsW + i * 8 * 64);
      gl_lds16(Bg + (size_t)(i * 8) * K + kt, BsW + i * 8 * 64);
    }
    __syncthreads();
    for (int kk = 0; kk < 2; ++kk) {
      bf16x8 af[4], bfr[4];
      for (int mi = 0; mi < 4; ++mi)
        af[mi] = *(const bf16x8*)(As + (wm * 64 + mi * 16 + fr) * 64 + kk * 32 + kg * 8);
      for (int ni = 0; ni < 4; ++ni)
        bfr[ni] = *(const bf16x8*)(Bs + (wn * 64 + ni * 16 + fr) * 64 + kk * 32 + kg * 8);
      for (int mi = 0; mi < 4; ++mi)
        for (int ni = 0; ni < 4; ++ni)
          acc[mi][ni] = __builtin_amdgcn_mfma_f32_16x16x32_bf16(af[mi], bfr[ni], acc[mi][ni], 0, 0, 0);
    }
  }
  for (int ni = 0; ni < 4; ++ni) {
    const int col = n0 + wn * 64 + ni * 16 + fr;
    const float bv = bias[col];
    for (int mi = 0; mi < 4; ++mi) {
      const int mbase = m0 + wm * 64 + mi * 16 + kg * 4;
      for (int r = 0; r < 4; ++r)
        out[(size_t)(mbase + r) * N_QKV + col] = (bf16)(acc[mi][ni][r] + bv);
    }
  }
}

__global__ __launch_bounds__(256) void k_out_gemm(const bf16* __restrict__ A,
                                                  const bf16* __restrict__ Bt,
                                                  const float* __restrict__ bias,
                                                  float* __restrict__ out) {
  __shared__ bf16 sm[2 * 128 * 64];
  bf16* As = sm;
  bf16* Bs = sm + 128 * 64;
  const int tid = threadIdx.x, wid = tid >> 6, lane = tid & 63;
  const int wm = wid >> 1, wn = wid & 1;
  const int fr = lane & 15, kg = lane >> 4;
  const int m0 = blockIdx.y * 128, n0 = blockIdx.x * 128;
  const int K = Ee;

  f32x4 acc[4][4] = {};

  const int ar = wid * 32 + (lane >> 3);
  const int ac = (lane & 7) * 8;
  const bf16* Ag = A + (size_t)(m0 + ar) * K + ac;
  const bf16* Bg = Bt + (size_t)(n0 + ar) * K + ac;
  bf16* AsW = As + wid * 32 * 64;
  bf16* BsW = Bs + wid * 32 * 64;

  for (int kt = 0; kt < K; kt += 64) {
    __syncthreads();
    for (int i = 0; i < 4; ++i) {
      gl_lds16(Ag + (size_t)(i * 8) * K + kt, AsW + i * 8 * 64);
      gl_lds16(Bg + (size_t)(i * 8) * K + kt, BsW + i * 8 * 64);
    }
    __syncthreads();
    for (int kk = 0; kk < 2; ++kk) {
      bf16x8 af[4], bfr[4];
      for (int mi = 0; mi < 4; ++mi)
        af[mi] = *(const bf16x8*)(As + (wm * 64 + mi * 16 + fr) * 64 + kk * 32 + kg * 8);
      for (int ni = 0; ni < 4; ++ni)
        bfr[ni] = *(const bf16x8*)(Bs + (wn * 64 + ni * 16 + fr) * 64 + kk * 32 + kg * 8);
      for (int mi = 0; mi < 4; ++mi)
        for (int ni = 0; ni < 4; ++ni)
          acc[mi][ni] = __builtin_amdgcn_mfma_f32_16x16x32_bf16(af[mi], bfr[ni], acc[mi][ni], 0, 0, 0);
    }
  }
  for (int ni = 0; ni < 4; ++ni) {
    const int col = n0 + wn * 64 + ni * 16 + fr;
    const float bv = bias[col];
    for (int mi = 0; mi < 4; ++mi) {
      const int mbase = m0 + wm * 64 + mi * 16 + kg * 4;
      for (int r = 0; r < 4; ++r)
        out[(size_t)(mbase + r) * Ee + col] = acc[mi][ni][r] + bv;
    }
  }
}

// ---------------- flash attention (causal, scale=1/32) ----------------
// q-block 128 (4 waves x 32 q-rows), KV tile 64, double-buffered K/V^T staging via
// global_load_lds with pre-swizzled sources; ONE barrier per tile; P per-wave via LDS.
// LPT dispatch: 1D grid, qt DESCENDS slowest so the 32-tile blocks launch first
// (work per block = 2*qt+2 tiles; heavy-first => balanced makespan ~68 tiles/CU).

__global__ __launch_bounds__(256, 2) void k_attn(const bf16* __restrict__ qkv,
                                                 const bf16* __restrict__ vt,
                                                 bf16* __restrict__ vals) {
  constexpr float SC = 0.03125f * 1.44269504f;  // (1/sqrt(E)) * log2(e)
  const int g = blockIdx.x;
  const int qt = 15 - (g >> 6);   // heavy blocks first
  const int bh = g & 63;
  const int b = bh >> 4, h = bh & 15;
  const int q0 = qt * 128;
  const int tid = threadIdx.x, w = tid >> 6, lane = tid & 63;
  const int fr = lane & 15, kg = lane >> 4;
  const int rl = lane >> 3, cl = (lane & 7) ^ (lane >> 3);

  __shared__ bf16 KsB[2][4096];   // [key 64][chunk-swizzled d 64]
  __shared__ bf16 VtB[2][4096];   // [d 64][chunk-swizzled s 64]
  __shared__ bf16 Ps[4][2048];    // per-wave [qrow 32][chunk-swizzled k 64]

  const bf16* base = qkv + (size_t)b * Ss * N_QKV + h * 192;
  const bf16* kb = base + 64 + (size_t)rl * N_QKV + cl * 8;
  const bf16* vb = vt + (size_t)(b * Hh + h) * 64 * Ss + (size_t)rl * Ss + cl * 8;

  // Q fragments in registers (32 rows/wave)
  bf16x8 aq[2][2];
  for (int sub = 0; sub < 2; ++sub) {
    const bf16* qr = base + (size_t)(q0 + w * 32 + sub * 16 + fr) * N_QKV + kg * 8;
    aq[sub][0] = *(const bf16x8*)(qr);
    aq[sub][1] = *(const bf16x8*)(qr + 32);
  }

  float m_run[2][4], l_run[2][4];
  f32x4 o_acc[2][4] = {};
  for (int s2 = 0; s2 < 2; ++s2)
    for (int r = 0; r < 4; ++r) { m_run[s2][r] = -1e30f; l_run[s2][r] = 0.f; }

  const int nt = 2 * qt + 2;

  // prologue: stage tile 0 into buf 0
  for (int t = 0; t < 2; ++t) {
    const int i = w * 2 + t;
    gl_lds16(kb + (size_t)(i * 8) * N_QKV, KsB[0] + i * 512);
    gl_lds16(vb + (size_t)(i * 8) * Ss, VtB[0] + i * 512);
  }

  int cur = 0;
  for (int it = 0; it < nt; ++it) {
    const int kv0 = it * 64;
    __syncthreads();  // drains vmcnt: stage(it) complete; prev-tile reads done
    if (it + 1 < nt) {
      const int kvn = kv0 + 64;
      for (int t = 0; t < 2; ++t) {
        const int i = w * 2 + t;
        gl_lds16(kb + (size_t)(kvn + i * 8) * N_QKV, KsB[cur ^ 1] + i * 512);
        gl_lds16(vb + (size_t)(i * 8) * Ss + kvn, VtB[cur ^ 1] + i * 512);
      }
    }
    const bool active = (kv0 <= q0 + w * 32 + 31);  // wave-uniform: any unmasked row?
    if (active) {
      // ---- QK^T ----
      f32x4 sacc[2][4] = {};
      for (int kk = 0; kk < 2; ++kk) {
        bf16x8 bk[4];
        for (int ni = 0; ni < 4; ++ni) {
          const int rb = ni * 16 + fr;
          bk[ni] = *(const bf16x8*)(KsB[cur] + rb * 64 + (((kk * 4 + kg) ^ (rb & 7)) * 8));
        }
        __builtin_amdgcn_s_setprio(1);
        for (int sub = 0; sub < 2; ++sub)
          for (int ni = 0; ni < 4; ++ni)
            sacc[sub][ni] =
                __builtin_amdgcn_mfma_f32_16x16x32_bf16(aq[sub][kk], bk[ni], sacc[sub][ni], 0, 0, 0);
        __builtin_amdgcn_s_setprio(0);
      }
      // ---- online softmax (exp2 domain) ----
      for (int sub = 0; sub < 2; ++sub) {
        const int qs = q0 + w * 32 + sub * 16;
        float pm[4] = {-1e30f, -1e30f, -1e30f, -1e30f};
        float p[4][4];
        if (kv0 + 63 > qs) {
          for (int ni = 0; ni < 4; ++ni) {
            const int kc = kv0 + ni * 16 + fr;
            for (int r = 0; r < 4; ++r) {
              float s = sacc[sub][ni][r] * SC;
              if (kc > qs + kg * 4 + r) s = -1e30f;
              p[ni][r] = s;
              pm[r] = fmaxf(pm[r], s);
            }
          }
        } else {
          for (int ni = 0; ni < 4; ++ni)
            for (int r = 0; r < 4; ++r) {
              float s = sacc[sub][ni][r] * SC;
              p[ni][r] = s;
              pm[r] = fmaxf(pm[r], s);
            }
        }
        for (int msk = 1; msk < 16; msk <<= 1)
          for (int r = 0; r < 4; ++r)
            pm[r] = fmaxf(pm[r], __shfl_xor(pm[r], msk, 64));
        float rs[4];
        for (int r = 0; r < 4; ++r) {
          const float mn = fmaxf(m_run[sub][r], pm[r]);
          const float f = exp2f(m_run[sub][r] - mn);
          m_run[sub][r] = mn;
          l_run[sub][r] *= f;
          for (int ni = 0; ni < 4; ++ni) o_acc[sub][ni][r] *= f;
          rs[r] = 0.f;
        }
        for (int ni = 0; ni < 4; ++ni)
          for (int r = 0; r < 4; ++r) {
            const float e = exp2f(p[ni][r] - m_run[sub][r]);
            p[ni][r] = e;
            rs[r] += e;
          }
        for (int msk = 1; msk < 16; msk <<= 1)
          for (int r = 0; r < 4; ++r)
            rs[r] += __shfl_xor(rs[r], msk, 64);
        for (int r = 0; r < 4; ++r) l_run[sub][r] += rs[r];
        // P -> per-wave LDS strip (swizzled); same-wave ordering, no barrier needed
        for (int ni = 0; ni < 4; ++ni) {
          const int kloc = ni * 16 + fr;
          const int ch = kloc >> 3, off = kloc & 7;
          for (int r = 0; r < 4; ++r) {
            const int qr = sub * 16 + kg * 4 + r;
            Ps[w][qr * 64 + ((ch ^ (qr & 7)) * 8) + off] = (bf16)p[ni][r];
          }
        }
      }
      // ---- O += P V ----
      for (int kk = 0; kk < 2; ++kk) {
        bf16x8 ap[2], bv[4];
        for (int sub = 0; sub < 2; ++sub) {
          const int pr = sub * 16 + fr;
          ap[sub] = *(const bf16x8*)(Ps[w] + pr * 64 + (((kk * 4 + kg) ^ (pr & 7)) * 8));
        }
        for (int ni = 0; ni < 4; ++ni) {
          const int rb = ni * 16 + fr;
          bv[ni] = *(const bf16x8*)(VtB[cur] + rb * 64 + (((kk * 4 + kg) ^ (rb & 7)) * 8));
        }
        __builtin_amdgcn_s_setprio(1);
        for (int sub = 0; sub < 2; ++sub)
          for (int ni = 0; ni < 4; ++ni)
            o_acc[sub][ni] =
                __builtin_amdgcn_mfma_f32_16x16x32_bf16(ap[sub], bv[ni], o_acc[sub][ni], 0, 0, 0);
        __builtin_amdgcn_s_setprio(0);
      }
    }
    cur ^= 1;
  }

  // epilogue: vals[b,s,h*64+d]
  for (int sub = 0; sub < 2; ++sub)
    for (int r = 0; r < 4; ++r) {
      const float inv = 1.f / l_run[sub][r];
      const int q = q0 + w * 32 + sub * 16 + kg * 4 + r;
      bf16* dst = vals + ((size_t)b * Ss + q) * Ee + h * 64;
      for (int ni = 0; ni < 4; ++ni)
        dst[ni * 16 + fr] = (bf16)(o_acc[sub][ni][r] * inv);
    }
}

// ---------------- launch ----------------

extern "C" void kernel_launch(void* const* d_in, const int* in_sizes, int n_in,
                              void* d_out, int out_size, void* d_ws, size_t ws_size,
                              hipStream_t stream) {
  const float* x    = (const float*)d_in[0];
  const float* Wqkv = (const float*)d_in[1];
  const float* bqkv = (const float*)d_in[2];
  const float* Wout = (const float*)d_in[3];
  const float* bout = (const float*)d_in[4];
  float* out = (float*)d_out;

  // workspace layout (92 MiB). vt reuses x_bf's region (x_bf dead after k_qkv_gemm).
  char* ws = (char*)d_ws;
  bf16* x_bf  = (bf16*)(ws);                               // 16 MiB  [8192,1024]
  bf16* vt    = (bf16*)(ws);                               // 16 MiB  [64,64,2048] (b*h, d, s)
  bf16* WqkvT = (bf16*)(ws + (size_t)16777216);            //  6 MiB  [3072,1024]
  bf16* WoutT = (bf16*)(ws + (size_t)16777216 + 6291456);  //  2 MiB  [1024,1024]
  bf16* qkvb  = (bf16*)(ws + (size_t)25165824);            // 48 MiB  [8192,3072]
  bf16* valsb = (bf16*)(ws + (size_t)75497472);            // 16 MiB  [8192,1024]

  k_cvt_bf16<<<dim3(Mm * Ee / 2048), dim3(256), 0, stream>>>(x, x_bf, Mm * Ee);
  k_transpose_cvt<<<dim3(N_QKV / 32, Ee / 32), dim3(32, 8), 0, stream>>>(Wqkv, WqkvT, Ee, N_QKV);
  k_transpose_cvt<<<dim3(Ee / 32, Ee / 32), dim3(32, 8), 0, stream>>>(Wout, WoutT, Ee, Ee);
  k_qkv_gemm<<<dim3(N_QKV / 128, Mm / 128), dim3(256), 0, stream>>>(x_bf, WqkvT, bqkv, qkvb);
  k_vt<<<dim3(Ss / 32, 2, Bb * Hh), dim3(32, 8), 0, stream>>>(qkvb, vt);
  k_attn<<<dim3(Ss / 128 * Hh * Bb), dim3(256), 0, stream>>>(qkvb, vt, valsb);
  k_out_gemm<<<dim3(Ee / 128, Mm / 128), dim3(256), 0, stream>>>(valsb, WoutT, bout, out);
}

// Round 4
// 223.774 us; speedup vs baseline: 2.0730x; 1.1805x over previous
//
#include <hip/hip_runtime.h>
#include <hip/hip_bf16.h>
#include <cstdint>
#include <cstddef>

typedef __bf16 bf16;
typedef __bf16 bf16x8 __attribute__((ext_vector_type(8)));
typedef float f32x4 __attribute__((ext_vector_type(4)));
typedef unsigned int u32x4 __attribute__((ext_vector_type(4)));
typedef unsigned int u32x2 __attribute__((ext_vector_type(2)));

#define DEVINL __device__ __forceinline__

namespace {
constexpr int Bb = 4, Ss = 2048, Ee = 1024, Hh = 16;
constexpr int Mm = Bb * Ss;      // 8192 rows
constexpr int N_QKV = 3 * Ee;    // 3072
}

DEVINL void gl_lds16(const bf16* g, bf16* l) {
  __builtin_amdgcn_global_load_lds((const __attribute__((address_space(1))) void*)g,
                                   (__attribute__((address_space(3))) void*)l, 16, 0, 0);
}

DEVINL unsigned int pkbf(float a, float b) {
  bf16 x = (bf16)a, y = (bf16)b;
  return (unsigned int)__builtin_bit_cast(unsigned short, x) |
         ((unsigned int)__builtin_bit_cast(unsigned short, y) << 16);
}

// ---------------- converters ----------------

__global__ void k_cvt_bf16(const float* __restrict__ in, bf16* __restrict__ out, int n) {
  int i = (blockIdx.x * 256 + threadIdx.x) * 8;
  if (i >= n) return;
  float4 a = *(const float4*)(in + i);
  float4 c = *(const float4*)(in + i + 4);
  bf16x8 v = {(bf16)a.x, (bf16)a.y, (bf16)a.z, (bf16)a.w,
              (bf16)c.x, (bf16)c.y, (bf16)c.z, (bf16)c.w};
  *(bf16x8*)(out + i) = v;
}

// out[c][r] = (bf16) in[r][c];  in: R x C f32 row-major. block (32,8), grid (C/32, R/32)
__global__ void k_transpose_cvt(const float* __restrict__ in, bf16* __restrict__ out, int R, int C) {
  __shared__ float tile[32][33];
  const int c0 = blockIdx.x * 32, r0 = blockIdx.y * 32;
  const int tx = threadIdx.x, ty = threadIdx.y;
  for (int i = 0; i < 32; i += 8)
    tile[ty + i][tx] = in[(size_t)(r0 + ty + i) * C + (c0 + tx)];
  __syncthreads();
  for (int i = 0; i < 32; i += 8)
    out[(size_t)(c0 + ty + i) * R + (r0 + tx)] = (bf16)tile[tx][ty + i];
}

// V^T extract: vt[b,h,d,s] = qkv[b,s,h*192 + 128 + d].  block (32,8), grid (S/32, D/32=2, B*H)
__global__ void k_vt(const bf16* __restrict__ qkvb, bf16* __restrict__ vt) {
  __shared__ bf16 t[32][33];
  const int bh = blockIdx.z;
  const int b = bh >> 4, h = bh & 15;
  const int s0 = blockIdx.x * 32, d0 = blockIdx.y * 32;
  const int tx = threadIdx.x, ty = threadIdx.y;
  const bf16* src = qkvb + (size_t)b * Ss * N_QKV + h * 192 + 128;
  for (int i = 0; i < 32; i += 8)
    t[ty + i][tx] = src[(size_t)(s0 + ty + i) * N_QKV + d0 + tx];
  __syncthreads();
  bf16* dst = vt + ((size_t)bh * 64 + d0) * Ss + s0;
  for (int i = 0; i < 32; i += 8)
    dst[(size_t)(ty + i) * Ss + tx] = t[tx][ty + i];
}

// ---------------- GEMM (A row-major MxK, Bt row-major NxK, bf16, f32 accum) ----------------

__global__ __launch_bounds__(256) void k_qkv_gemm(const bf16* __restrict__ A,
                                                  const bf16* __restrict__ Bt,
                                                  const float* __restrict__ bias,
                                                  bf16* __restrict__ out) {
  __shared__ bf16 sm[2 * 128 * 64];
  bf16* As = sm;
  bf16* Bs = sm + 128 * 64;
  const int tid = threadIdx.x, wid = tid >> 6, lane = tid & 63;
  const int wm = wid >> 1, wn = wid & 1;
  const int fr = lane & 15, kg = lane >> 4;
  const int m0 = blockIdx.y * 128, n0 = blockIdx.x * 128;
  const int K = Ee;

  f32x4 acc[4][4] = {};

  const int ar = wid * 32 + (lane >> 3);
  const int ac = (lane & 7) * 8;
  const bf16* Ag = A + (size_t)(m0 + ar) * K + ac;
  const bf16* Bg = Bt + (size_t)(n0 + ar) * K + ac;
  bf16* AsW = As + wid * 32 * 64;
  bf16* BsW = Bs + wid * 32 * 64;

  for (int kt = 0; kt < K; kt += 64) {
    __syncthreads();
    for (int i = 0; i < 4; ++i) {
      gl_lds16(Ag + (size_t)(i * 8) * K + kt, AsW + i * 8 * 64);
      gl_lds16(Bg + (size_t)(i * 8) * K + kt, BsW + i * 8 * 64);
    }
    __syncthreads();
    for (int kk = 0; kk < 2; ++kk) {
      bf16x8 af[4], bfr[4];
      for (int mi = 0; mi < 4; ++mi)
        af[mi] = *(const bf16x8*)(As + (wm * 64 + mi * 16 + fr) * 64 + kk * 32 + kg * 8);
      for (int ni = 0; ni < 4; ++ni)
        bfr[ni] = *(const bf16x8*)(Bs + (wn * 64 + ni * 16 + fr) * 64 + kk * 32 + kg * 8);
      for (int mi = 0; mi < 4; ++mi)
        for (int ni = 0; ni < 4; ++ni)
          acc[mi][ni] = __builtin_amdgcn_mfma_f32_16x16x32_bf16(af[mi], bfr[ni], acc[mi][ni], 0, 0, 0);
    }
  }
  for (int ni = 0; ni < 4; ++ni) {
    const int col = n0 + wn * 64 + ni * 16 + fr;
    const float bv = bias[col];
    for (int mi = 0; mi < 4; ++mi) {
      const int mbase = m0 + wm * 64 + mi * 16 + kg * 4;
      for (int r = 0; r < 4; ++r)
        out[(size_t)(mbase + r) * N_QKV + col] = (bf16)(acc[mi][ni][r] + bv);
    }
  }
}

__global__ __launch_bounds__(256) void k_out_gemm(const bf16* __restrict__ A,
                                                  const bf16* __restrict__ Bt,
                                                  const float* __restrict__ bias,
                                                  float* __restrict__ out) {
  __shared__ bf16 sm[2 * 128 * 64];
  bf16* As = sm;
  bf16* Bs = sm + 128 * 64;
  const int tid = threadIdx.x, wid = tid >> 6, lane = tid & 63;
  const int wm = wid >> 1, wn = wid & 1;
  const int fr = lane & 15, kg = lane >> 4;
  const int m0 = blockIdx.y * 128, n0 = blockIdx.x * 128;
  const int K = Ee;

  f32x4 acc[4][4] = {};

  const int ar = wid * 32 + (lane >> 3);
  const int ac = (lane & 7) * 8;
  const bf16* Ag = A + (size_t)(m0 + ar) * K + ac;
  const bf16* Bg = Bt + (size_t)(n0 + ar) * K + ac;
  bf16* AsW = As + wid * 32 * 64;
  bf16* BsW = Bs + wid * 32 * 64;

  for (int kt = 0; kt < K; kt += 64) {
    __syncthreads();
    for (int i = 0; i < 4; ++i) {
      gl_lds16(Ag + (size_t)(i * 8) * K + kt, AsW + i * 8 * 64);
      gl_lds16(Bg + (size_t)(i * 8) * K + kt, BsW + i * 8 * 64);
    }
    __syncthreads();
    for (int kk = 0; kk < 2; ++kk) {
      bf16x8 af[4], bfr[4];
      for (int mi = 0; mi < 4; ++mi)
        af[mi] = *(const bf16x8*)(As + (wm * 64 + mi * 16 + fr) * 64 + kk * 32 + kg * 8);
      for (int ni = 0; ni < 4; ++ni)
        bfr[ni] = *(const bf16x8*)(Bs + (wn * 64 + ni * 16 + fr) * 64 + kk * 32 + kg * 8);
      for (int mi = 0; mi < 4; ++mi)
        for (int ni = 0; ni < 4; ++ni)
          acc[mi][ni] = __builtin_amdgcn_mfma_f32_16x16x32_bf16(af[mi], bfr[ni], acc[mi][ni], 0, 0, 0);
    }
  }
  for (int ni = 0; ni < 4; ++ni) {
    const int col = n0 + wn * 64 + ni * 16 + fr;
    const float bv = bias[col];
    for (int mi = 0; mi < 4; ++mi) {
      const int mbase = m0 + wm * 64 + mi * 16 + kg * 4;
      for (int r = 0; r < 4; ++r)
        out[(size_t)(mbase + r) * Ee + col] = acc[mi][ni][r] + bv;
    }
  }
}

// ---------------- flash attention (causal, scale=1/32) ----------------
// Swapped-operand structure (T12-style): S^T = mfma(K,Q) so each lane holds one q-row's
// P values in registers -> in-lane softmax (2 shfl per reduce), P repacked in-register
// (shfl exchange) straight into PV's B-operand; O accumulated transposed. No P LDS.
// LPT dispatch: qt descends so 32-tile blocks launch first.

__global__ __launch_bounds__(256, 3) void k_attn(const bf16* __restrict__ qkv,
                                                 const bf16* __restrict__ vt,
                                                 bf16* __restrict__ vals) {
  constexpr float SC = 0.03125f * 1.44269504f;  // (1/sqrt(E)) * log2(e)
  const int g = blockIdx.x;
  const int qt = 15 - (g >> 6);   // heavy blocks first
  const int bh = g & 63;
  const int b = bh >> 4, h = bh & 15;
  const int q0 = qt * 128;
  const int tid = threadIdx.x, w = tid >> 6, lane = tid & 63;
  const int fr = lane & 15, kg = lane >> 4;
  const int rl = lane >> 3, cl = (lane & 7) ^ (lane >> 3);

  __shared__ bf16 KsB[2][4096];   // [key 64][chunk-swizzled d 64]
  __shared__ bf16 VtB[2][4096];   // [d 64][chunk-swizzled s 64]

  const bf16* base = qkv + (size_t)b * Ss * N_QKV + h * 192;
  const bf16* kb = base + 64 + (size_t)rl * N_QKV + cl * 8;
  const bf16* vb = vt + (size_t)(b * Hh + h) * 64 * Ss + (size_t)rl * Ss + cl * 8;

  // shfl source lanes for the P repack (per-thread constants)
  const int gA = (kg & 1) * 32 + fr;   // group (kg&1)*2, same fr
  const int gB = gA + 16;              // group (kg&1)*2+1
  const bool hiSel = (kg >> 1) != 0;   // selects ni = 2*kk + (kg>>1)

  // Q fragments in registers (32 rows/wave)
  bf16x8 aq[2][2];
  for (int sub = 0; sub < 2; ++sub) {
    const bf16* qr = base + (size_t)(q0 + w * 32 + sub * 16 + fr) * N_QKV + kg * 8;
    aq[sub][0] = *(const bf16x8*)(qr);
    aq[sub][1] = *(const bf16x8*)(qr + 32);
  }

  float m_run[2] = {-1e30f, -1e30f}, l_run[2] = {0.f, 0.f};
  f32x4 o_acc[2][4] = {};   // O^T: o_acc[sub][d-tile]; col=fr=q, row=kg*4+r=d-local

  const int nt = 2 * qt + 2;

  // prologue: stage tile 0 into buf 0
  for (int t = 0; t < 2; ++t) {
    const int i = w * 2 + t;
    gl_lds16(kb + (size_t)(i * 8) * N_QKV, KsB[0] + i * 512);
    gl_lds16(vb + (size_t)(i * 8) * Ss, VtB[0] + i * 512);
  }

  int cur = 0;
  for (int it = 0; it < nt; ++it) {
    const int kv0 = it * 64;
    __syncthreads();  // drains vmcnt: stage(it) complete; prev-tile reads done
    if (it + 1 < nt) {
      const int kvn = kv0 + 64;
      for (int t = 0; t < 2; ++t) {
        const int i = w * 2 + t;
        gl_lds16(kb + (size_t)(kvn + i * 8) * N_QKV, KsB[cur ^ 1] + i * 512);
        gl_lds16(vb + (size_t)(i * 8) * Ss + kvn, VtB[cur ^ 1] + i * 512);
      }
    }
    const bool active = (kv0 <= q0 + w * 32 + 31);  // wave-uniform
    if (active) {
      // ---- S^T = K Q (swapped operands; same fragments, A<->B) ----
      f32x4 sacc[2][4] = {};
      for (int kk = 0; kk < 2; ++kk) {
        bf16x8 bk[4];
        for (int ni = 0; ni < 4; ++ni) {
          const int rb = ni * 16 + fr;
          bk[ni] = *(const bf16x8*)(KsB[cur] + rb * 64 + (((kk * 4 + kg) ^ (rb & 7)) * 8));
        }
        __builtin_amdgcn_s_setprio(1);
        for (int sub = 0; sub < 2; ++sub)
          for (int ni = 0; ni < 4; ++ni)
            sacc[sub][ni] =
                __builtin_amdgcn_mfma_f32_16x16x32_bf16(bk[ni], aq[sub][kk], sacc[sub][ni], 0, 0, 0);
        __builtin_amdgcn_s_setprio(0);
      }
      // ---- softmax, in-lane (lane owns q = qs+fr; k = kv0 + ni*16 + kg*4 + r) ----
      bf16x8 bp[2][2];  // [sub][kk] PV B-operand fragments
      for (int sub = 0; sub < 2; ++sub) {
        const int qs = q0 + w * 32 + sub * 16;
        float p[4][4];
        float mnew = -1e30f;
        if (kv0 + 63 > qs) {
          const int q = qs + fr;
          for (int ni = 0; ni < 4; ++ni)
            for (int r = 0; r < 4; ++r) {
              const int k = kv0 + ni * 16 + kg * 4 + r;
              float s = sacc[sub][ni][r] * SC;
              if (k > q) s = -1e30f;
              p[ni][r] = s;
              mnew = fmaxf(mnew, s);
            }
        } else {
          for (int ni = 0; ni < 4; ++ni)
            for (int r = 0; r < 4; ++r) {
              float s = sacc[sub][ni][r] * SC;
              p[ni][r] = s;
              mnew = fmaxf(mnew, s);
            }
        }
        mnew = fmaxf(mnew, __shfl_xor(mnew, 16, 64));
        mnew = fmaxf(mnew, __shfl_xor(mnew, 32, 64));
        const float mn = fmaxf(m_run[sub], mnew);
        const float fs = exp2f(m_run[sub] - mn);
        m_run[sub] = mn;
        float rs = 0.f;
        for (int ni = 0; ni < 4; ++ni)
          for (int r = 0; r < 4; ++r) {
            const float e = exp2f(p[ni][r] - mn);
            p[ni][r] = e;
            rs += e;
          }
        rs += __shfl_xor(rs, 16, 64);
        rs += __shfl_xor(rs, 32, 64);
        l_run[sub] = l_run[sub] * fs + rs;
        for (int ni = 0; ni < 4; ++ni)
          for (int r = 0; r < 4; ++r)
            o_acc[sub][ni][r] *= fs;
        // pack p -> bf16 word pairs per k-subtile
        unsigned int Wlo[4], Whi[4];
        for (int ni = 0; ni < 4; ++ni) {
          Wlo[ni] = pkbf(p[ni][0], p[ni][1]);
          Whi[ni] = pkbf(p[ni][2], p[ni][3]);
        }
        // exchange: lane (fr,kg) gathers P^T[k=kk*32+kg*8+j][q=fr]
        for (int kk = 0; kk < 2; ++kk) {
          const int i0 = 2 * kk, i1 = 2 * kk + 1;
          unsigned int a0 = (unsigned int)__shfl((int)Wlo[i0], gA, 64);
          unsigned int a1 = (unsigned int)__shfl((int)Wlo[i1], gA, 64);
          unsigned int b0 = (unsigned int)__shfl((int)Whi[i0], gA, 64);
          unsigned int b1 = (unsigned int)__shfl((int)Whi[i1], gA, 64);
          unsigned int c0 = (unsigned int)__shfl((int)Wlo[i0], gB, 64);
          unsigned int c1 = (unsigned int)__shfl((int)Wlo[i1], gB, 64);
          unsigned int d0 = (unsigned int)__shfl((int)Whi[i0], gB, 64);
          unsigned int d1 = (unsigned int)__shfl((int)Whi[i1], gB, 64);
          u32x4 wv = {hiSel ? a1 : a0, hiSel ? b1 : b0, hiSel ? c1 : c0, hiSel ? d1 : d0};
          bp[sub][kk] = __builtin_bit_cast(bf16x8, wv);
        }
      }
      // ---- O^T += V^T P^T ----
      for (int kk = 0; kk < 2; ++kk) {
        bf16x8 bv[4];
        for (int ni = 0; ni < 4; ++ni) {
          const int rb = ni * 16 + fr;
          bv[ni] = *(const bf16x8*)(VtB[cur] + rb * 64 + (((kk * 4 + kg) ^ (rb & 7)) * 8));
        }
        __builtin_amdgcn_s_setprio(1);
        for (int sub = 0; sub < 2; ++sub)
          for (int ni = 0; ni < 4; ++ni)
            o_acc[sub][ni] =
                __builtin_amdgcn_mfma_f32_16x16x32_bf16(bv[ni], bp[sub][kk], o_acc[sub][ni], 0, 0, 0);
        __builtin_amdgcn_s_setprio(0);
      }
    }
    cur ^= 1;
  }

  // epilogue: O^T -> vals[b, q, h*64+d]; lane owns q=qs+fr, d = ni*16+kg*4+{0..3}
  for (int sub = 0; sub < 2; ++sub) {
    const float inv = 1.f / l_run[sub];
    const int q = q0 + w * 32 + sub * 16 + fr;
    bf16* dst = vals + ((size_t)b * Ss + q) * Ee + h * 64 + kg * 4;
    for (int ni = 0; ni < 4; ++ni) {
      u32x2 pk2 = {pkbf(o_acc[sub][ni][0] * inv, o_acc[sub][ni][1] * inv),
                   pkbf(o_acc[sub][ni][2] * inv, o_acc[sub][ni][3] * inv)};
      *(u32x2*)(dst + ni * 16) = pk2;
    }
  }
}

// ---------------- launch ----------------

extern "C" void kernel_launch(void* const* d_in, const int* in_sizes, int n_in,
                              void* d_out, int out_size, void* d_ws, size_t ws_size,
                              hipStream_t stream) {
  const float* x    = (const float*)d_in[0];
  const float* Wqkv = (const float*)d_in[1];
  const float* bqkv = (const float*)d_in[2];
  const float* Wout = (const float*)d_in[3];
  const float* bout = (const float*)d_in[4];
  float* out = (float*)d_out;

  // workspace layout (92 MiB). vt reuses x_bf's region (x_bf dead after k_qkv_gemm).
  char* ws = (char*)d_ws;
  bf16* x_bf  = (bf16*)(ws);                               // 16 MiB  [8192,1024]
  bf16* vt    = (bf16*)(ws);                               // 16 MiB  [64,64,2048] (b*h, d, s)
  bf16* WqkvT = (bf16*)(ws + (size_t)16777216);            //  6 MiB  [3072,1024]
  bf16* WoutT = (bf16*)(ws + (size_t)16777216 + 6291456);  //  2 MiB  [1024,1024]
  bf16* qkvb  = (bf16*)(ws + (size_t)25165824);            // 48 MiB  [8192,3072]
  bf16* valsb = (bf16*)(ws + (size_t)75497472);            // 16 MiB  [8192,1024]

  k_cvt_bf16<<<dim3(Mm * Ee / 2048), dim3(256), 0, stream>>>(x, x_bf, Mm * Ee);
  k_transpose_cvt<<<dim3(N_QKV / 32, Ee / 32), dim3(32, 8), 0, stream>>>(Wqkv, WqkvT, Ee, N_QKV);
  k_transpose_cvt<<<dim3(Ee / 32, Ee / 32), dim3(32, 8), 0, stream>>>(Wout, WoutT, Ee, Ee);
  k_qkv_gemm<<<dim3(N_QKV / 128, Mm / 128), dim3(256), 0, stream>>>(x_bf, WqkvT, bqkv, qkvb);
  k_vt<<<dim3(Ss / 32, 2, Bb * Hh), dim3(32, 8), 0, stream>>>(qkvb, vt);
  k_attn<<<dim3(Ss / 128 * Hh * Bb), dim3(256), 0, stream>>>(qkvb, vt, valsb);
  k_out_gemm<<<dim3(Ee / 128, Mm / 128), dim3(256), 0, stream>>>(valsb, WoutT, bout, out);
}